// Round 1
// 408.495 us; speedup vs baseline: 1.0395x; 1.0395x over previous
//
#include <hip/hip_runtime.h>
#include <hip/hip_bf16.h>

#define FEAT 1024
#define EMBED 128
#define CAP 64          // per-node bucket capacity (Poisson mean deg = 16)
#define OVF_CAP 4096    // overflow list capacity

typedef __attribute__((ext_vector_type(8))) short short8;
typedef __attribute__((ext_vector_type(4))) float floatx4;

__device__ inline ushort f2bf(float f) {
    __hip_bfloat16 h = __float2bfloat16(f);
    return *reinterpret_cast<ushort*>(&h);
}
__device__ inline float bfbits_lo(uint u) {        // low 16 bits as bf16 -> f32
    uint v = u << 16; return *reinterpret_cast<float*>(&v);
}
__device__ inline float bfbits_hi(uint u) {        // high 16 bits as bf16 -> f32
    uint v = u & 0xffff0000u; return *reinterpret_cast<float*>(&v);
}

// --- kernel 1: W fp32 -> bf16, swizzled into MFMA-fragment-linear order ------
// wbs[((s*8 + t)*64 + lane)*8 + j] = bf16(W[t*16 + (lane&15)][s*32 + (lane>>4)*8 + j])
__global__ void swizzle_weight_kernel(const float* __restrict__ w,
                                      ushort* __restrict__ wbs) {
    int gid = blockIdx.x * blockDim.x + threadIdx.x;   // 16384 threads
    int l = gid & 63;
    int t = (gid >> 6) & 7;
    int s = gid >> 9;
    int row = t * 16 + (l & 15);
    int col = s * 32 + (l >> 4) * 8;
    const float* src = w + (size_t)row * FEAT + col;
    float4 v0 = *(const float4*)(src);
    float4 v1 = *(const float4*)(src + 4);
    short8 o;
    o[0] = f2bf(v0.x); o[1] = f2bf(v0.y); o[2] = f2bf(v0.z); o[3] = f2bf(v0.w);
    o[4] = f2bf(v1.x); o[5] = f2bf(v1.y); o[6] = f2bf(v1.z); o[7] = f2bf(v1.w);
    *(short8*)(wbs + (size_t)gid * 8) = o;
}

// --- kernel 2: h = x @ W^T via bf16 MFMA, h stored bf16 ----------------------
// block = 128 = 2 waves; each wave handles 32 rows x 128 embeds (2 A-frags x
// 8 B-frags = 16 MFMA per k-step, 12 VMEM). Halves per-wave W traffic vs the
// 16-row version (total W L2 reads 800MB -> 400MB) and raises MFMA density.
__launch_bounds__(128, 3)
__global__ void gemm_xwT_kernel(const float* __restrict__ x,
                                const ushort* __restrict__ wbs,
                                ushort* __restrict__ hb, int n_nodes) {
    const int lane = threadIdx.x & 63;
    const int wave = threadIdx.x >> 6;
    const int q    = lane >> 4;
    const int m    = lane & 15;
    const int base = blockIdx.x * 64 + wave * 32;

    int row0 = base + m;
    int row1 = base + 16 + m;
    int r0l = row0 < n_nodes ? row0 : (n_nodes - 1);
    int r1l = row1 < n_nodes ? row1 : (n_nodes - 1);
    const float*  xp0 = x + (size_t)r0l * FEAT + q * 8;
    const float*  xp1 = x + (size_t)r1l * FEAT + q * 8;
    const ushort* bp  = wbs + lane * 8;

    floatx4 acc[2][8];
#pragma unroll
    for (int rf = 0; rf < 2; ++rf)
#pragma unroll
        for (int t = 0; t < 8; ++t) acc[rf][t] = (floatx4)(0.0f);

    float4 a00 = *(const float4*)(xp0);
    float4 a01 = *(const float4*)(xp0 + 4);
    float4 a10 = *(const float4*)(xp1);
    float4 a11 = *(const float4*)(xp1 + 4);

    for (int s = 0; s < 32; ++s) {
        float4 n00, n01, n10, n11;
        if (s < 31) {                       // prefetch next A chunk (both frag rows)
            n00 = *(const float4*)(xp0 + (s + 1) * 32);
            n01 = *(const float4*)(xp0 + (s + 1) * 32 + 4);
            n10 = *(const float4*)(xp1 + (s + 1) * 32);
            n11 = *(const float4*)(xp1 + (s + 1) * 32 + 4);
        }
        // batch-load all 8 B fragments (independent -> 8 loads in flight)
        const ushort* bs = bp + s * 4096;
        short8 bf[8];
#pragma unroll
        for (int t = 0; t < 8; ++t) bf[t] = *(const short8*)(bs + t * 512);

        short8 af0, af1;
        af0[0] = f2bf(a00.x); af0[1] = f2bf(a00.y);
        af0[2] = f2bf(a00.z); af0[3] = f2bf(a00.w);
        af0[4] = f2bf(a01.x); af0[5] = f2bf(a01.y);
        af0[6] = f2bf(a01.z); af0[7] = f2bf(a01.w);
        af1[0] = f2bf(a10.x); af1[1] = f2bf(a10.y);
        af1[2] = f2bf(a10.z); af1[3] = f2bf(a10.w);
        af1[4] = f2bf(a11.x); af1[5] = f2bf(a11.y);
        af1[6] = f2bf(a11.z); af1[7] = f2bf(a11.w);

#pragma unroll
        for (int t = 0; t < 8; ++t) {
            acc[0][t] = __builtin_amdgcn_mfma_f32_16x16x32_bf16(af0, bf[t], acc[0][t], 0, 0, 0);
            acc[1][t] = __builtin_amdgcn_mfma_f32_16x16x32_bf16(af1, bf[t], acc[1][t], 0, 0, 0);
        }
        a00 = n00; a01 = n01; a10 = n10; a11 = n11;
    }

#pragma unroll
    for (int rf = 0; rf < 2; ++rf) {
#pragma unroll
        for (int t = 0; t < 8; ++t) {
#pragma unroll
            for (int r = 0; r < 4; ++r) {
                int rr = base + rf * 16 + q * 4 + r;
                if (rr < n_nodes)
                    hb[(size_t)rr * EMBED + t * 16 + m] = f2bf(acc[rf][t][r]);
            }
        }
    }
}

// --- kernel 3: bucket edges by destination -----------------------------------
__global__ void bucket_fill_kernel(const int* __restrict__ adj_row,
                                   const int* __restrict__ adj_col,
                                   const float* __restrict__ adj_vals,
                                   int* __restrict__ cnt,
                                   int2* __restrict__ bucket,
                                   int* __restrict__ ovf_cnt,
                                   int* __restrict__ ovf_list,
                                   int n_edges) {
    int e = blockIdx.x * blockDim.x + threadIdx.x;
    if (e >= n_edges) return;
    int r = adj_row[e];
    int slot = atomicAdd(&cnt[r], 1);
    if (slot < CAP) {
        bucket[(size_t)r * CAP + slot] = make_int2(adj_col[e], __float_as_int(adj_vals[e]));
    } else {
        int oi = atomicAdd(ovf_cnt, 1);
        if (oi < OVF_CAP) ovf_list[oi] = e;
    }
}

// --- kernel 4: per-node gather-accumulate, MLP-8, scalar bucket reads --------
// 4 nodes per 256-thread block (1 wave per node). node is forced into an SGPR
// (readfirstlane) so cnt/bucket reads go through the scalar path (s_load),
// edge weights stay in SGPRs, and gather loads use SGPR-base + lane voffset.
// 8 h-row gathers in flight per wave to cover LLC latency.
__launch_bounds__(256)
__global__ void gather_kernel(const int* __restrict__ cnt,
                              const int2* __restrict__ bucket,
                              const ushort* __restrict__ hb,
                              float* __restrict__ out, int n_nodes) {
    int node = __builtin_amdgcn_readfirstlane(blockIdx.x * 4 + (threadIdx.x >> 6));
    if (node >= n_nodes) return;
    int lane = threadIdx.x & 63;
    int c = cnt[node];
    if (c > CAP) c = CAP;
    const int2* bp = bucket + (size_t)node * CAP;
    const ushort* hl = hb + lane * 2;       // per-lane column offset (bf16x2)

    float accx = 0.0f, accy = 0.0f;
    int j = 0;
    for (; j + 8 <= c; j += 8) {
        int4 e01 = *(const int4*)(bp + j);
        int4 e23 = *(const int4*)(bp + j + 2);
        int4 e45 = *(const int4*)(bp + j + 4);
        int4 e67 = *(const int4*)(bp + j + 6);
        uint u0 = *(const uint*)(hl + (size_t)e01.x * EMBED);
        uint u1 = *(const uint*)(hl + (size_t)e01.z * EMBED);
        uint u2 = *(const uint*)(hl + (size_t)e23.x * EMBED);
        uint u3 = *(const uint*)(hl + (size_t)e23.z * EMBED);
        uint u4 = *(const uint*)(hl + (size_t)e45.x * EMBED);
        uint u5 = *(const uint*)(hl + (size_t)e45.z * EMBED);
        uint u6 = *(const uint*)(hl + (size_t)e67.x * EMBED);
        uint u7 = *(const uint*)(hl + (size_t)e67.z * EMBED);
        float w0 = __int_as_float(e01.y), w1 = __int_as_float(e01.w);
        float w2 = __int_as_float(e23.y), w3 = __int_as_float(e23.w);
        float w4 = __int_as_float(e45.y), w5 = __int_as_float(e45.w);
        float w6 = __int_as_float(e67.y), w7 = __int_as_float(e67.w);
        accx = fmaf(w0, bfbits_lo(u0), accx);  accy = fmaf(w0, bfbits_hi(u0), accy);
        accx = fmaf(w1, bfbits_lo(u1), accx);  accy = fmaf(w1, bfbits_hi(u1), accy);
        accx = fmaf(w2, bfbits_lo(u2), accx);  accy = fmaf(w2, bfbits_hi(u2), accy);
        accx = fmaf(w3, bfbits_lo(u3), accx);  accy = fmaf(w3, bfbits_hi(u3), accy);
        accx = fmaf(w4, bfbits_lo(u4), accx);  accy = fmaf(w4, bfbits_hi(u4), accy);
        accx = fmaf(w5, bfbits_lo(u5), accx);  accy = fmaf(w5, bfbits_hi(u5), accy);
        accx = fmaf(w6, bfbits_lo(u6), accx);  accy = fmaf(w6, bfbits_hi(u6), accy);
        accx = fmaf(w7, bfbits_lo(u7), accx);  accy = fmaf(w7, bfbits_hi(u7), accy);
    }
    for (; j + 2 <= c; j += 2) {
        int4 e01 = *(const int4*)(bp + j);
        uint u0 = *(const uint*)(hl + (size_t)e01.x * EMBED);
        uint u1 = *(const uint*)(hl + (size_t)e01.z * EMBED);
        float w0 = __int_as_float(e01.y), w1 = __int_as_float(e01.w);
        accx = fmaf(w0, bfbits_lo(u0), accx);  accy = fmaf(w0, bfbits_hi(u0), accy);
        accx = fmaf(w1, bfbits_lo(u1), accx);  accy = fmaf(w1, bfbits_hi(u1), accy);
    }
    if (j < c) {
        int2 ev = bp[j];
        uint u = *(const uint*)(hl + (size_t)ev.x * EMBED);
        float w = __int_as_float(ev.y);
        accx = fmaf(w, bfbits_lo(u), accx);
        accy = fmaf(w, bfbits_hi(u), accy);
    }
    *(float2*)(out + (size_t)node * EMBED + lane * 2) = make_float2(accx, accy);
}

// --- kernel 5: exact fixup for bucket overflow (expected n=0) ----------------
__global__ void overflow_fixup_kernel(const int* __restrict__ ovf_cnt,
                                      const int* __restrict__ ovf_list,
                                      const int* __restrict__ adj_row,
                                      const int* __restrict__ adj_col,
                                      const float* __restrict__ adj_vals,
                                      const ushort* __restrict__ hb,
                                      float* __restrict__ out) {
    int n = *ovf_cnt;
    if (n > OVF_CAP) n = OVF_CAP;
    int f = threadIdx.x;                                  // 128 threads
    for (int i = blockIdx.x; i < n; i += gridDim.x) {
        int e = ovf_list[i];
        uint us = hb[(size_t)adj_col[e] * EMBED + f];
        uint v = us << 16;
        atomicAdd(&out[(size_t)adj_row[e] * EMBED + f],
                  adj_vals[e] * *reinterpret_cast<float*>(&v));
    }
}

extern "C" void kernel_launch(void* const* d_in, const int* in_sizes, int n_in,
                              void* d_out, int out_size, void* d_ws, size_t ws_size,
                              hipStream_t stream) {
    const float* x        = (const float*)d_in[0];
    const float* w        = (const float*)d_in[1];
    const int*   adj_row  = (const int*)d_in[2];
    const int*   adj_col  = (const int*)d_in[3];
    const float* adj_vals = (const float*)d_in[4];

    const int n_nodes = in_sizes[0] / FEAT;
    const int n_edges = in_sizes[2];
    float* out = (float*)d_out;

    // workspace layout (bytes):
    //   [wbs 256KB][hb n*128*2][cnt n*4][ovf_cnt 4][ovf_list][pad->16][bucket n*CAP*8]
    char* ws = (char*)d_ws;
    ushort* wbs = (ushort*)ws;
    size_t off = 262144;
    ushort* hb = (ushort*)(ws + off);
    off += (size_t)n_nodes * EMBED * sizeof(ushort);
    char* meta = ws + off;
    int* cnt      = (int*)meta;
    int* ovf_cnt  = (int*)(meta + (size_t)n_nodes * 4);
    int* ovf_list = ovf_cnt + 1;
    size_t meta_bytes = ((size_t)n_nodes * 4 + 4 + OVF_CAP * 4 + 15) & ~(size_t)15;
    int2* bucket = (int2*)(meta + meta_bytes);

    hipMemsetAsync(meta, 0, meta_bytes, stream);

    swizzle_weight_kernel<<<64, 256, 0, stream>>>(w, wbs);

    gemm_xwT_kernel<<<(n_nodes + 63) / 64, 128, 0, stream>>>(x, wbs, hb, n_nodes);

    bucket_fill_kernel<<<(n_edges + 255) / 256, 256, 0, stream>>>(
        adj_row, adj_col, adj_vals, cnt, bucket, ovf_cnt, ovf_list, n_edges);

    gather_kernel<<<(n_nodes + 3) / 4, 256, 0, stream>>>(cnt, bucket, hb, out, n_nodes);

    overflow_fixup_kernel<<<64, 128, 0, stream>>>(
        ovf_cnt, ovf_list, adj_row, adj_col, adj_vals, hb, out);
}

// Round 2
// 390.789 us; speedup vs baseline: 1.0866x; 1.0453x over previous
//
#include <hip/hip_runtime.h>
#include <hip/hip_bf16.h>

#define FEAT 1024
#define EMBED 128
#define CAP 64          // per-node bucket capacity (Poisson mean deg = 16)
#define OVF_CAP 4096    // overflow list capacity

typedef __attribute__((ext_vector_type(8))) short short8;
typedef __attribute__((ext_vector_type(4))) float floatx4;

__device__ inline ushort f2bf(float f) {
    __hip_bfloat16 h = __float2bfloat16(f);
    return *reinterpret_cast<ushort*>(&h);
}
__device__ inline float bfbits_lo(uint u) {        // low 16 bits as bf16 -> f32
    uint v = u << 16; return *reinterpret_cast<float*>(&v);
}
__device__ inline float bfbits_hi(uint u) {        // high 16 bits as bf16 -> f32
    uint v = u & 0xffff0000u; return *reinterpret_cast<float*>(&v);
}

// async 16B global -> LDS (wave-uniform LDS base + lane*16, per-lane global src)
__device__ inline void async_copy16(const void* g, void* l) {
    __builtin_amdgcn_global_load_lds(
        (const __attribute__((address_space(1))) void*)g,
        (__attribute__((address_space(3))) void*)l, 16, 0, 0);
}

// --- kernel 1: W fp32 -> bf16, swizzled into MFMA-fragment-linear order ------
// wbs[((s*8 + t)*64 + lane)*8 + j] = bf16(W[t*16 + (lane&15)][s*32 + (lane>>4)*8 + j])
__global__ void swizzle_weight_kernel(const float* __restrict__ w,
                                      ushort* __restrict__ wbs) {
    int gid = blockIdx.x * blockDim.x + threadIdx.x;   // 16384 threads
    int l = gid & 63;
    int t = (gid >> 6) & 7;
    int s = gid >> 9;
    int row = t * 16 + (l & 15);
    int col = s * 32 + (l >> 4) * 8;
    const float* src = w + (size_t)row * FEAT + col;
    float4 v0 = *(const float4*)(src);
    float4 v1 = *(const float4*)(src + 4);
    short8 o;
    o[0] = f2bf(v0.x); o[1] = f2bf(v0.y); o[2] = f2bf(v0.z); o[3] = f2bf(v0.w);
    o[4] = f2bf(v1.x); o[5] = f2bf(v1.y); o[6] = f2bf(v1.z); o[7] = f2bf(v1.w);
    *(short8*)(wbs + (size_t)gid * 8) = o;
}

// --- kernel 2: h = x @ W^T via bf16 MFMA, h stored bf16 ----------------------
// 256 thr = 4 waves x 32 rows = 128 rows/block. B (swizzled W) is staged into
// LDS chunk-by-chunk (chunk = 4 k-steps = 32 KB, double-buffered) via
// global_load_lds, so B consumption waits on lgkmcnt (ds_read) and is NEVER
// gated by the in-order vmcnt drain of the A (x, HBM) prefetch stream.
// A is register-batched one chunk (4 k-steps) at a time: its ~900-cyc HBM
// latency is paid once per chunk at the barrier drain, not once per k-step.
__launch_bounds__(256, 2)
__global__ void gemm_xwT_kernel(const float* __restrict__ x,
                                const ushort* __restrict__ wbs,
                                ushort* __restrict__ hb, int n_nodes) {
    __shared__ ushort lds[2][16384];            // 2 x 32 KB chunk buffers

    const int lane = threadIdx.x & 63;
    const int wave = threadIdx.x >> 6;
    const int q    = lane >> 4;
    const int m    = lane & 15;
    const int base = blockIdx.x * 128 + wave * 32;

    int row0 = base + m;
    int row1 = base + 16 + m;
    int r0l = row0 < n_nodes ? row0 : (n_nodes - 1);
    int r1l = row1 < n_nodes ? row1 : (n_nodes - 1);
    const float* xp0 = x + (size_t)r0l * FEAT + q * 8;
    const float* xp1 = x + (size_t)r1l * FEAT + q * 8;

    const char* wb = (const char*)wbs;
    // per-wave staging: wave w copies instrs w*8..w*8+7 (1 KB each) of a 32 KB chunk
    const size_t stage_src_off = (size_t)(wave * 8 * 64 + lane) * 16;
    const int    stage_dst_off = wave * 8192;   // bytes within chunk buffer

    // stage chunk 0
    {
        const char* src = wb + stage_src_off;
        char* dst = (char*)lds[0] + stage_dst_off;
#pragma unroll
        for (int k = 0; k < 8; ++k)
            async_copy16(src + k * 1024, dst + k * 1024);
    }

    // A batch for chunk 0 (4 k-steps): [u][frag0.lo, frag0.hi, frag1.lo, frag1.hi]
    float4 A[4][4];
#pragma unroll
    for (int u = 0; u < 4; ++u) {
        A[u][0] = *(const float4*)(xp0 + u * 32);
        A[u][1] = *(const float4*)(xp0 + u * 32 + 4);
        A[u][2] = *(const float4*)(xp1 + u * 32);
        A[u][3] = *(const float4*)(xp1 + u * 32 + 4);
    }

    floatx4 acc[2][8];
#pragma unroll
    for (int rf = 0; rf < 2; ++rf)
#pragma unroll
        for (int t = 0; t < 8; ++t) acc[rf][t] = (floatx4)(0.0f);

    __syncthreads();                            // drains stage[0] + A[0]

    for (int c = 0; c < 8; ++c) {
        const ushort* buf = lds[c & 1];
        if (c < 7) {                            // stage next chunk into other buffer
            const char* src = wb + (size_t)(c + 1) * 32768 + stage_src_off;
            char* dst = (char*)lds[(c + 1) & 1] + stage_dst_off;
#pragma unroll
            for (int k = 0; k < 8; ++k)
                async_copy16(src + k * 1024, dst + k * 1024);
        }
#pragma unroll
        for (int u = 0; u < 4; ++u) {
            // B fragments from LDS: ushort idx ((u*8 + t)*64 + lane)*8
            const ushort* bs = buf + u * 4096 + lane * 8;
            short8 bf[8];
#pragma unroll
            for (int t = 0; t < 8; ++t) bf[t] = *(const short8*)(bs + t * 512);

            short8 af0, af1;
            af0[0] = f2bf(A[u][0].x); af0[1] = f2bf(A[u][0].y);
            af0[2] = f2bf(A[u][0].z); af0[3] = f2bf(A[u][0].w);
            af0[4] = f2bf(A[u][1].x); af0[5] = f2bf(A[u][1].y);
            af0[6] = f2bf(A[u][1].z); af0[7] = f2bf(A[u][1].w);
            af1[0] = f2bf(A[u][2].x); af1[1] = f2bf(A[u][2].y);
            af1[2] = f2bf(A[u][2].z); af1[3] = f2bf(A[u][2].w);
            af1[4] = f2bf(A[u][3].x); af1[5] = f2bf(A[u][3].y);
            af1[6] = f2bf(A[u][3].z); af1[7] = f2bf(A[u][3].w);

            if (u == 3 && c < 7) {              // reload A batch for chunk c+1
                const float* p0 = xp0 + (c + 1) * 128;
                const float* p1 = xp1 + (c + 1) * 128;
#pragma unroll
                for (int uu = 0; uu < 4; ++uu) {
                    A[uu][0] = *(const float4*)(p0 + uu * 32);
                    A[uu][1] = *(const float4*)(p0 + uu * 32 + 4);
                    A[uu][2] = *(const float4*)(p1 + uu * 32);
                    A[uu][3] = *(const float4*)(p1 + uu * 32 + 4);
                }
            }
#pragma unroll
            for (int t = 0; t < 8; ++t) {
                acc[0][t] = __builtin_amdgcn_mfma_f32_16x16x32_bf16(af0, bf[t], acc[0][t], 0, 0, 0);
                acc[1][t] = __builtin_amdgcn_mfma_f32_16x16x32_bf16(af1, bf[t], acc[1][t], 0, 0, 0);
            }
        }
        __syncthreads();                        // buf reuse fence + drains stage/A
    }

#pragma unroll
    for (int rf = 0; rf < 2; ++rf) {
#pragma unroll
        for (int t = 0; t < 8; ++t) {
#pragma unroll
            for (int r = 0; r < 4; ++r) {
                int rr = base + rf * 16 + q * 4 + r;
                if (rr < n_nodes)
                    hb[(size_t)rr * EMBED + t * 16 + m] = f2bf(acc[rf][t][r]);
            }
        }
    }
}

// --- kernel 3: bucket edges by destination -----------------------------------
__global__ void bucket_fill_kernel(const int* __restrict__ adj_row,
                                   const int* __restrict__ adj_col,
                                   const float* __restrict__ adj_vals,
                                   int* __restrict__ cnt,
                                   int2* __restrict__ bucket,
                                   int* __restrict__ ovf_cnt,
                                   int* __restrict__ ovf_list,
                                   int n_edges) {
    int e = blockIdx.x * blockDim.x + threadIdx.x;
    if (e >= n_edges) return;
    int r = adj_row[e];
    int slot = atomicAdd(&cnt[r], 1);
    if (slot < CAP) {
        bucket[(size_t)r * CAP + slot] = make_int2(adj_col[e], __float_as_int(adj_vals[e]));
    } else {
        int oi = atomicAdd(ovf_cnt, 1);
        if (oi < OVF_CAP) ovf_list[oi] = e;
    }
}

// --- kernel 4: per-node gather-accumulate, MLP-8, scalar bucket reads --------
__launch_bounds__(256)
__global__ void gather_kernel(const int* __restrict__ cnt,
                              const int2* __restrict__ bucket,
                              const ushort* __restrict__ hb,
                              float* __restrict__ out, int n_nodes) {
    int node = __builtin_amdgcn_readfirstlane(blockIdx.x * 4 + (threadIdx.x >> 6));
    if (node >= n_nodes) return;
    int lane = threadIdx.x & 63;
    int c = cnt[node];
    if (c > CAP) c = CAP;
    const int2* bp = bucket + (size_t)node * CAP;
    const ushort* hl = hb + lane * 2;       // per-lane column offset (bf16x2)

    float accx = 0.0f, accy = 0.0f;
    int j = 0;
    for (; j + 8 <= c; j += 8) {
        int4 e01 = *(const int4*)(bp + j);
        int4 e23 = *(const int4*)(bp + j + 2);
        int4 e45 = *(const int4*)(bp + j + 4);
        int4 e67 = *(const int4*)(bp + j + 6);
        uint u0 = *(const uint*)(hl + (size_t)e01.x * EMBED);
        uint u1 = *(const uint*)(hl + (size_t)e01.z * EMBED);
        uint u2 = *(const uint*)(hl + (size_t)e23.x * EMBED);
        uint u3 = *(const uint*)(hl + (size_t)e23.z * EMBED);
        uint u4 = *(const uint*)(hl + (size_t)e45.x * EMBED);
        uint u5 = *(const uint*)(hl + (size_t)e45.z * EMBED);
        uint u6 = *(const uint*)(hl + (size_t)e67.x * EMBED);
        uint u7 = *(const uint*)(hl + (size_t)e67.z * EMBED);
        float w0 = __int_as_float(e01.y), w1 = __int_as_float(e01.w);
        float w2 = __int_as_float(e23.y), w3 = __int_as_float(e23.w);
        float w4 = __int_as_float(e45.y), w5 = __int_as_float(e45.w);
        float w6 = __int_as_float(e67.y), w7 = __int_as_float(e67.w);
        accx = fmaf(w0, bfbits_lo(u0), accx);  accy = fmaf(w0, bfbits_hi(u0), accy);
        accx = fmaf(w1, bfbits_lo(u1), accx);  accy = fmaf(w1, bfbits_hi(u1), accy);
        accx = fmaf(w2, bfbits_lo(u2), accx);  accy = fmaf(w2, bfbits_hi(u2), accy);
        accx = fmaf(w3, bfbits_lo(u3), accx);  accy = fmaf(w3, bfbits_hi(u3), accy);
        accx = fmaf(w4, bfbits_lo(u4), accx);  accy = fmaf(w4, bfbits_hi(u4), accy);
        accx = fmaf(w5, bfbits_lo(u5), accx);  accy = fmaf(w5, bfbits_hi(u5), accy);
        accx = fmaf(w6, bfbits_lo(u6), accx);  accy = fmaf(w6, bfbits_hi(u6), accy);
        accx = fmaf(w7, bfbits_lo(u7), accx);  accy = fmaf(w7, bfbits_hi(u7), accy);
    }
    for (; j + 2 <= c; j += 2) {
        int4 e01 = *(const int4*)(bp + j);
        uint u0 = *(const uint*)(hl + (size_t)e01.x * EMBED);
        uint u1 = *(const uint*)(hl + (size_t)e01.z * EMBED);
        float w0 = __int_as_float(e01.y), w1 = __int_as_float(e01.w);
        accx = fmaf(w0, bfbits_lo(u0), accx);  accy = fmaf(w0, bfbits_hi(u0), accy);
        accx = fmaf(w1, bfbits_lo(u1), accx);  accy = fmaf(w1, bfbits_hi(u1), accy);
    }
    if (j < c) {
        int2 ev = bp[j];
        uint u = *(const uint*)(hl + (size_t)ev.x * EMBED);
        float w = __int_as_float(ev.y);
        accx = fmaf(w, bfbits_lo(u), accx);
        accy = fmaf(w, bfbits_hi(u), accy);
    }
    *(float2*)(out + (size_t)node * EMBED + lane * 2) = make_float2(accx, accy);
}

// --- kernel 5: exact fixup for bucket overflow (expected n=0) ----------------
__global__ void overflow_fixup_kernel(const int* __restrict__ ovf_cnt,
                                      const int* __restrict__ ovf_list,
                                      const int* __restrict__ adj_row,
                                      const int* __restrict__ adj_col,
                                      const float* __restrict__ adj_vals,
                                      const ushort* __restrict__ hb,
                                      float* __restrict__ out) {
    int n = *ovf_cnt;
    if (n > OVF_CAP) n = OVF_CAP;
    int f = threadIdx.x;                                  // 128 threads
    for (int i = blockIdx.x; i < n; i += gridDim.x) {
        int e = ovf_list[i];
        uint us = hb[(size_t)adj_col[e] * EMBED + f];
        uint v = us << 16;
        atomicAdd(&out[(size_t)adj_row[e] * EMBED + f],
                  adj_vals[e] * *reinterpret_cast<float*>(&v));
    }
}

extern "C" void kernel_launch(void* const* d_in, const int* in_sizes, int n_in,
                              void* d_out, int out_size, void* d_ws, size_t ws_size,
                              hipStream_t stream) {
    const float* x        = (const float*)d_in[0];
    const float* w        = (const float*)d_in[1];
    const int*   adj_row  = (const int*)d_in[2];
    const int*   adj_col  = (const int*)d_in[3];
    const float* adj_vals = (const float*)d_in[4];

    const int n_nodes = in_sizes[0] / FEAT;
    const int n_edges = in_sizes[2];
    float* out = (float*)d_out;

    // workspace layout (bytes):
    //   [wbs 256KB][hb n*128*2][cnt n*4][ovf_cnt 4][ovf_list][pad->16][bucket n*CAP*8]
    char* ws = (char*)d_ws;
    ushort* wbs = (ushort*)ws;
    size_t off = 262144;
    ushort* hb = (ushort*)(ws + off);
    off += (size_t)n_nodes * EMBED * sizeof(ushort);
    char* meta = ws + off;
    int* cnt      = (int*)meta;
    int* ovf_cnt  = (int*)(meta + (size_t)n_nodes * 4);
    int* ovf_list = ovf_cnt + 1;
    size_t meta_bytes = ((size_t)n_nodes * 4 + 4 + OVF_CAP * 4 + 15) & ~(size_t)15;
    int2* bucket = (int2*)(meta + meta_bytes);

    hipMemsetAsync(meta, 0, meta_bytes, stream);

    swizzle_weight_kernel<<<64, 256, 0, stream>>>(w, wbs);

    gemm_xwT_kernel<<<(n_nodes + 127) / 128, 256, 0, stream>>>(x, wbs, hb, n_nodes);

    bucket_fill_kernel<<<(n_edges + 255) / 256, 256, 0, stream>>>(
        adj_row, adj_col, adj_vals, cnt, bucket, ovf_cnt, ovf_list, n_edges);

    gather_kernel<<<(n_nodes + 3) / 4, 256, 0, stream>>>(cnt, bucket, hb, out, n_nodes);

    overflow_fixup_kernel<<<64, 128, 0, stream>>>(
        ovf_cnt, ovf_list, adj_row, adj_col, adj_vals, hb, out);
}

// Round 3
// 365.868 us; speedup vs baseline: 1.1606x; 1.0681x over previous
//
#include <hip/hip_runtime.h>
#include <hip/hip_bf16.h>

#define FEAT 1024
#define EMBED 128
#define CAP 64          // per-node bucket capacity (Poisson mean deg = 16)
#define OVF_CAP 4096    // overflow list capacity

typedef __attribute__((ext_vector_type(8))) short short8;
typedef __attribute__((ext_vector_type(4))) float floatx4;

__device__ inline ushort f2bf(float f) {
    __hip_bfloat16 h = __float2bfloat16(f);
    return *reinterpret_cast<ushort*>(&h);
}
__device__ inline float bfbits_lo(uint u) {        // low 16 bits as bf16 -> f32
    uint v = u << 16; return *reinterpret_cast<float*>(&v);
}
__device__ inline float bfbits_hi(uint u) {        // high 16 bits as bf16 -> f32
    uint v = u & 0xffff0000u; return *reinterpret_cast<float*>(&v);
}

// async 16B global -> LDS (wave-uniform LDS base + lane*16, per-lane global src)
__device__ inline void async_copy16(const void* g, void* l) {
    __builtin_amdgcn_global_load_lds(
        (const __attribute__((address_space(1))) void*)g,
        (__attribute__((address_space(3))) void*)l, 16, 0, 0);
}

// --- kernel 1: W fp32 -> bf16, swizzled into MFMA-fragment-linear order ------
// wbs[((s*8 + t)*64 + lane)*8 + j] = bf16(W[t*16 + (lane&15)][s*32 + (lane>>4)*8 + j])
__global__ void swizzle_weight_kernel(const float* __restrict__ w,
                                      ushort* __restrict__ wbs) {
    int gid = blockIdx.x * blockDim.x + threadIdx.x;   // 16384 threads
    int l = gid & 63;
    int t = (gid >> 6) & 7;
    int s = gid >> 9;
    int row = t * 16 + (l & 15);
    int col = s * 32 + (l >> 4) * 8;
    const float* src = w + (size_t)row * FEAT + col;
    float4 v0 = *(const float4*)(src);
    float4 v1 = *(const float4*)(src + 4);
    short8 o;
    o[0] = f2bf(v0.x); o[1] = f2bf(v0.y); o[2] = f2bf(v0.z); o[3] = f2bf(v0.w);
    o[4] = f2bf(v1.x); o[5] = f2bf(v1.y); o[6] = f2bf(v1.z); o[7] = f2bf(v1.w);
    *(short8*)(wbs + (size_t)gid * 8) = o;
}

// --- kernel 2: merged [GEMM h = x@W^T] + [edge bucketing] --------------------
// Blocks < gemm_blocks: 4 waves x 32 rows = 128 rows/block of bf16 MFMA GEMM.
//   B (swizzled W) staged to LDS via global_load_lds (waits on lgkmcnt, never
//   gated by the A vmcnt stream). A prefetch for chunk c+1 is split: half at
//   u==1 into dead A[0..1], half at u==3 into dead A[2..3] (earlier issue =
//   more latency cover, zero extra VGPR).
// Blocks >= gemm_blocks: bucket edges by destination (independent of GEMM;
//   ~3 us of chip work that hides entirely under the HBM-bound GEMM).
__launch_bounds__(256, 2)
__global__ void gemm_bucket_kernel(const float* __restrict__ x,
                                   const ushort* __restrict__ wbs,
                                   ushort* __restrict__ hb, int n_nodes,
                                   const int* __restrict__ adj_row,
                                   const int* __restrict__ adj_col,
                                   const float* __restrict__ adj_vals,
                                   int* __restrict__ cnt,
                                   int2* __restrict__ bucket,
                                   int* __restrict__ ovf_cnt,
                                   int* __restrict__ ovf_list,
                                   int n_edges, int gemm_blocks) {
    __shared__ ushort lds[2][16384];            // 2 x 32 KB chunk buffers

    if (blockIdx.x >= gemm_blocks) {
        // ---------------- bucket-fill role ----------------
        int e = (blockIdx.x - gemm_blocks) * 256 + threadIdx.x;
        if (e < n_edges) {
            int r = adj_row[e];
            int slot = atomicAdd(&cnt[r], 1);
            if (slot < CAP) {
                bucket[(size_t)r * CAP + slot] =
                    make_int2(adj_col[e], __float_as_int(adj_vals[e]));
            } else {
                int oi = atomicAdd(ovf_cnt, 1);
                if (oi < OVF_CAP) ovf_list[oi] = e;
            }
        }
        return;
    }

    // ---------------- GEMM role ----------------
    const int lane = threadIdx.x & 63;
    const int wave = threadIdx.x >> 6;
    const int q    = lane >> 4;
    const int m    = lane & 15;
    const int base = blockIdx.x * 128 + wave * 32;

    int row0 = base + m;
    int row1 = base + 16 + m;
    int r0l = row0 < n_nodes ? row0 : (n_nodes - 1);
    int r1l = row1 < n_nodes ? row1 : (n_nodes - 1);
    const float* xp0 = x + (size_t)r0l * FEAT + q * 8;
    const float* xp1 = x + (size_t)r1l * FEAT + q * 8;

    const char* wb = (const char*)wbs;
    // per-wave staging: wave w copies 8 x 1 KB slices of a 32 KB chunk
    const size_t stage_src_off = (size_t)(wave * 8 * 64 + lane) * 16;
    const int    stage_dst_off = wave * 8192;   // bytes within chunk buffer

    // stage chunk 0
    {
        const char* src = wb + stage_src_off;
        char* dst = (char*)lds[0] + stage_dst_off;
#pragma unroll
        for (int k = 0; k < 8; ++k)
            async_copy16(src + k * 1024, dst + k * 1024);
    }

    // A batch for chunk 0 (4 k-steps): [u][frag0.lo, frag0.hi, frag1.lo, frag1.hi]
    float4 A[4][4];
#pragma unroll
    for (int u = 0; u < 4; ++u) {
        A[u][0] = *(const float4*)(xp0 + u * 32);
        A[u][1] = *(const float4*)(xp0 + u * 32 + 4);
        A[u][2] = *(const float4*)(xp1 + u * 32);
        A[u][3] = *(const float4*)(xp1 + u * 32 + 4);
    }

    floatx4 acc[2][8];
#pragma unroll
    for (int rf = 0; rf < 2; ++rf)
#pragma unroll
        for (int t = 0; t < 8; ++t) acc[rf][t] = (floatx4)(0.0f);

    __syncthreads();                            // drains stage[0] + A[0]

    for (int c = 0; c < 8; ++c) {
        const ushort* buf = lds[c & 1];
        if (c < 7) {                            // stage next chunk into other buffer
            const char* src = wb + (size_t)(c + 1) * 32768 + stage_src_off;
            char* dst = (char*)lds[(c + 1) & 1] + stage_dst_off;
#pragma unroll
            for (int k = 0; k < 8; ++k)
                async_copy16(src + k * 1024, dst + k * 1024);
        }
#pragma unroll
        for (int u = 0; u < 4; ++u) {
            // B fragments from LDS: ushort idx ((u*8 + t)*64 + lane)*8
            const ushort* bs = buf + u * 4096 + lane * 8;
            short8 bf[8];
#pragma unroll
            for (int t = 0; t < 8; ++t) bf[t] = *(const short8*)(bs + t * 512);

            short8 af0, af1;
            af0[0] = f2bf(A[u][0].x); af0[1] = f2bf(A[u][0].y);
            af0[2] = f2bf(A[u][0].z); af0[3] = f2bf(A[u][0].w);
            af0[4] = f2bf(A[u][1].x); af0[5] = f2bf(A[u][1].y);
            af0[6] = f2bf(A[u][1].z); af0[7] = f2bf(A[u][1].w);
            af1[0] = f2bf(A[u][2].x); af1[1] = f2bf(A[u][2].y);
            af1[2] = f2bf(A[u][2].z); af1[3] = f2bf(A[u][2].w);
            af1[4] = f2bf(A[u][3].x); af1[5] = f2bf(A[u][3].y);
            af1[6] = f2bf(A[u][3].z); af1[7] = f2bf(A[u][3].w);

            // prefetch next chunk's A into just-consumed (dead) A slots:
            // u==1 -> A[0..1] (covered by u=1..3 MFMAs), u==3 -> A[2..3]
            if (c < 7) {
                const float* p0 = xp0 + (c + 1) * 128;
                const float* p1 = xp1 + (c + 1) * 128;
                if (u == 1) {
#pragma unroll
                    for (int uu = 0; uu < 2; ++uu) {
                        A[uu][0] = *(const float4*)(p0 + uu * 32);
                        A[uu][1] = *(const float4*)(p0 + uu * 32 + 4);
                        A[uu][2] = *(const float4*)(p1 + uu * 32);
                        A[uu][3] = *(const float4*)(p1 + uu * 32 + 4);
                    }
                } else if (u == 3) {
#pragma unroll
                    for (int uu = 2; uu < 4; ++uu) {
                        A[uu][0] = *(const float4*)(p0 + uu * 32);
                        A[uu][1] = *(const float4*)(p0 + uu * 32 + 4);
                        A[uu][2] = *(const float4*)(p1 + uu * 32);
                        A[uu][3] = *(const float4*)(p1 + uu * 32 + 4);
                    }
                }
            }
#pragma unroll
            for (int t = 0; t < 8; ++t) {
                acc[0][t] = __builtin_amdgcn_mfma_f32_16x16x32_bf16(af0, bf[t], acc[0][t], 0, 0, 0);
                acc[1][t] = __builtin_amdgcn_mfma_f32_16x16x32_bf16(af1, bf[t], acc[1][t], 0, 0, 0);
            }
        }
        __syncthreads();                        // buf reuse fence + drains stage/A
    }

#pragma unroll
    for (int rf = 0; rf < 2; ++rf) {
#pragma unroll
        for (int t = 0; t < 8; ++t) {
#pragma unroll
            for (int r = 0; r < 4; ++r) {
                int rr = base + rf * 16 + q * 4 + r;
                if (rr < n_nodes)
                    hb[(size_t)rr * EMBED + t * 16 + m] = f2bf(acc[rf][t][r]);
            }
        }
    }
}

// --- kernel 3: per-node gather-accumulate + inline overflow fixup ------------
// 4 nodes per 256-thread block (1 wave per node). node forced into SGPR so
// cnt/bucket reads use the scalar path; gather loads are SGPR-base + lane
// voffset, 8 in flight. Nodes whose raw count exceeded CAP scan the overflow
// list themselves (expected empty -> one scalar load + compare per wave).
__launch_bounds__(256)
__global__ void gather_kernel(const int* __restrict__ cnt,
                              const int2* __restrict__ bucket,
                              const ushort* __restrict__ hb,
                              const int* __restrict__ ovf_cnt,
                              const int* __restrict__ ovf_list,
                              const int* __restrict__ adj_row,
                              const int* __restrict__ adj_col,
                              const float* __restrict__ adj_vals,
                              float* __restrict__ out, int n_nodes) {
    int node = __builtin_amdgcn_readfirstlane(blockIdx.x * 4 + (threadIdx.x >> 6));
    if (node >= n_nodes) return;
    int lane = threadIdx.x & 63;
    int c_raw = cnt[node];
    int c = c_raw > CAP ? CAP : c_raw;
    const int2* bp = bucket + (size_t)node * CAP;
    const ushort* hl = hb + lane * 2;       // per-lane column offset (bf16x2)

    float accx = 0.0f, accy = 0.0f;
    int j = 0;
    for (; j + 8 <= c; j += 8) {
        int4 e01 = *(const int4*)(bp + j);
        int4 e23 = *(const int4*)(bp + j + 2);
        int4 e45 = *(const int4*)(bp + j + 4);
        int4 e67 = *(const int4*)(bp + j + 6);
        uint u0 = *(const uint*)(hl + (size_t)e01.x * EMBED);
        uint u1 = *(const uint*)(hl + (size_t)e01.z * EMBED);
        uint u2 = *(const uint*)(hl + (size_t)e23.x * EMBED);
        uint u3 = *(const uint*)(hl + (size_t)e23.z * EMBED);
        uint u4 = *(const uint*)(hl + (size_t)e45.x * EMBED);
        uint u5 = *(const uint*)(hl + (size_t)e45.z * EMBED);
        uint u6 = *(const uint*)(hl + (size_t)e67.x * EMBED);
        uint u7 = *(const uint*)(hl + (size_t)e67.z * EMBED);
        float w0 = __int_as_float(e01.y), w1 = __int_as_float(e01.w);
        float w2 = __int_as_float(e23.y), w3 = __int_as_float(e23.w);
        float w4 = __int_as_float(e45.y), w5 = __int_as_float(e45.w);
        float w6 = __int_as_float(e67.y), w7 = __int_as_float(e67.w);
        accx = fmaf(w0, bfbits_lo(u0), accx);  accy = fmaf(w0, bfbits_hi(u0), accy);
        accx = fmaf(w1, bfbits_lo(u1), accx);  accy = fmaf(w1, bfbits_hi(u1), accy);
        accx = fmaf(w2, bfbits_lo(u2), accx);  accy = fmaf(w2, bfbits_hi(u2), accy);
        accx = fmaf(w3, bfbits_lo(u3), accx);  accy = fmaf(w3, bfbits_hi(u3), accy);
        accx = fmaf(w4, bfbits_lo(u4), accx);  accy = fmaf(w4, bfbits_hi(u4), accy);
        accx = fmaf(w5, bfbits_lo(u5), accx);  accy = fmaf(w5, bfbits_hi(u5), accy);
        accx = fmaf(w6, bfbits_lo(u6), accx);  accy = fmaf(w6, bfbits_hi(u6), accy);
        accx = fmaf(w7, bfbits_lo(u7), accx);  accy = fmaf(w7, bfbits_hi(u7), accy);
    }
    for (; j + 2 <= c; j += 2) {
        int4 e01 = *(const int4*)(bp + j);
        uint u0 = *(const uint*)(hl + (size_t)e01.x * EMBED);
        uint u1 = *(const uint*)(hl + (size_t)e01.z * EMBED);
        float w0 = __int_as_float(e01.y), w1 = __int_as_float(e01.w);
        accx = fmaf(w0, bfbits_lo(u0), accx);  accy = fmaf(w0, bfbits_hi(u0), accy);
        accx = fmaf(w1, bfbits_lo(u1), accx);  accy = fmaf(w1, bfbits_hi(u1), accy);
    }
    if (j < c) {
        int2 ev = bp[j];
        uint u = *(const uint*)(hl + (size_t)ev.x * EMBED);
        float w = __int_as_float(ev.y);
        accx = fmaf(w, bfbits_lo(u), accx);
        accy = fmaf(w, bfbits_hi(u), accy);
    }
    if (c_raw > CAP) {                        // inline overflow fixup (expected 0)
        int n = *ovf_cnt;
        if (n > OVF_CAP) n = OVF_CAP;
        for (int i = 0; i < n; ++i) {
            int e = ovf_list[i];
            if (adj_row[e] == node) {
                uint u = *(const uint*)(hl + (size_t)adj_col[e] * EMBED);
                float w = adj_vals[e];
                accx = fmaf(w, bfbits_lo(u), accx);
                accy = fmaf(w, bfbits_hi(u), accy);
            }
        }
    }
    *(float2*)(out + (size_t)node * EMBED + lane * 2) = make_float2(accx, accy);
}

extern "C" void kernel_launch(void* const* d_in, const int* in_sizes, int n_in,
                              void* d_out, int out_size, void* d_ws, size_t ws_size,
                              hipStream_t stream) {
    const float* x        = (const float*)d_in[0];
    const float* w        = (const float*)d_in[1];
    const int*   adj_row  = (const int*)d_in[2];
    const int*   adj_col  = (const int*)d_in[3];
    const float* adj_vals = (const float*)d_in[4];

    const int n_nodes = in_sizes[0] / FEAT;
    const int n_edges = in_sizes[2];
    float* out = (float*)d_out;

    // workspace layout (bytes):
    //   [wbs 256KB][hb n*128*2][cnt n*4][ovf_cnt 4][ovf_list][pad->16][bucket n*CAP*8]
    char* ws = (char*)d_ws;
    ushort* wbs = (ushort*)ws;
    size_t off = 262144;
    ushort* hb = (ushort*)(ws + off);
    off += (size_t)n_nodes * EMBED * sizeof(ushort);
    char* meta = ws + off;
    int* cnt      = (int*)meta;
    int* ovf_cnt  = (int*)(meta + (size_t)n_nodes * 4);
    int* ovf_list = ovf_cnt + 1;
    size_t meta_bytes = ((size_t)n_nodes * 4 + 4 + OVF_CAP * 4 + 15) & ~(size_t)15;
    int2* bucket = (int2*)(meta + meta_bytes);

    hipMemsetAsync(meta, 0, meta_bytes, stream);

    swizzle_weight_kernel<<<64, 256, 0, stream>>>(w, wbs);

    const int gemm_blocks   = (n_nodes + 127) / 128;
    const int bucket_blocks = (n_edges + 255) / 256;
    gemm_bucket_kernel<<<gemm_blocks + bucket_blocks, 256, 0, stream>>>(
        x, wbs, hb, n_nodes,
        adj_row, adj_col, adj_vals,
        cnt, bucket, ovf_cnt, ovf_list, n_edges, gemm_blocks);

    gather_kernel<<<(n_nodes + 3) / 4, 256, 0, stream>>>(
        cnt, bucket, hb, ovf_cnt, ovf_list, adj_row, adj_col, adj_vals,
        out, n_nodes);
}